// Round 1
// baseline (7878.716 us; speedup 1.0000x reference)
//
#include <hip/hip_runtime.h>
#include <cmath>

#define NN 1024
#define BC 128
#define LS 24

__device__ __forceinline__ float sigf(float x){ return 1.0f/(1.0f+expf(-x)); }

// ---------------- preprocessing ----------------

// X[t][i][n] = inputs[(i*NN+n)*LS + t]   (time-major transpose)
__global__ void k_transpose(const float* __restrict__ in, float* __restrict__ X){
  int idx = blockIdx.x*256 + threadIdx.x;           // over LS*BC*NN
  int n = idx & 1023; int ti = idx >> 10; int i = ti & 127; int t = ti >> 7;
  X[idx] = in[(size_t)(i*1024 + n)*24 + t];
}

// tmp[j] = sum_i adj[i,j]; zeros -> 1e-5
__global__ void k_colsum(const float* __restrict__ adj, float* __restrict__ tmp){
  int j = blockIdx.x*256 + threadIdx.x;
  float s = 0.f;
  for (int i = 0; i < 1024; ++i) s += adj[(size_t)i*1024 + j];
  tmp[j] = (s == 0.f) ? 1e-5f : s;
}

// anorm[i,j] = tmp[i]*adj[i,j];  A1 = min(anorm, 1)
__global__ void k_anorm(const float* __restrict__ adj, const float* __restrict__ tmp,
                        float* __restrict__ anorm, float* __restrict__ A1){
  int idx = blockIdx.x*256 + threadIdx.x;           // 1M
  int i = idx >> 10;
  float v = tmp[i]*adj[idx];
  anorm[idx] = v;
  A1[idx] = fminf(v, 1.f);
}

// C = min(A@B, 1), 1024x1024x1024, NN layout. 64x64 tile, 256 thr, 4x4/thr.
__global__ __launch_bounds__(256) void k_gemm_nn(const float* __restrict__ A,
                                                 const float* __restrict__ B,
                                                 float* __restrict__ C){
  __shared__ float As[16][64];
  __shared__ float Bs[16][64];
  int i0 = blockIdx.y*64, j0 = blockIdx.x*64;
  int tid = threadIdx.x;
  int tx = tid & 15, ty = tid >> 4;
  float acc[4][4] = {};
  for (int k0 = 0; k0 < 1024; k0 += 16) {
    {
      int m = tid >> 2, kq = tid & 3;
      float4 v = *(const float4*)(A + (size_t)(i0+m)*1024 + k0 + kq*4);
      As[kq*4+0][m]=v.x; As[kq*4+1][m]=v.y; As[kq*4+2][m]=v.z; As[kq*4+3][m]=v.w;
    }
    {
      int k = tid >> 6, j = tid & 63;
      #pragma unroll
      for (int r = 0; r < 4; ++r)
        Bs[k + r*4][j] = B[(size_t)(k0 + k + r*4)*1024 + j0 + j];
    }
    __syncthreads();
    #pragma unroll
    for (int k = 0; k < 16; ++k) {
      float4 a = *(const float4*)&As[k][ty*4];
      float4 b = *(const float4*)&Bs[k][tx*4];
      acc[0][0]+=a.x*b.x; acc[0][1]+=a.x*b.y; acc[0][2]+=a.x*b.z; acc[0][3]+=a.x*b.w;
      acc[1][0]+=a.y*b.x; acc[1][1]+=a.y*b.y; acc[1][2]+=a.y*b.z; acc[1][3]+=a.y*b.w;
      acc[2][0]+=a.z*b.x; acc[2][1]+=a.z*b.y; acc[2][2]+=a.z*b.z; acc[2][3]+=a.z*b.w;
      acc[3][0]+=a.w*b.x; acc[3][1]+=a.w*b.y; acc[3][2]+=a.w*b.z; acc[3][3]+=a.w*b.w;
    }
    __syncthreads();
  }
  #pragma unroll
  for (int r = 0; r < 4; ++r) {
    float4 o4 = make_float4(fminf(acc[r][0],1.f), fminf(acc[r][1],1.f),
                            fminf(acc[r][2],1.f), fminf(acc[r][3],1.f));
    *(float4*)(C + (size_t)(i0+ty*4+r)*1024 + j0 + tx*4) = o4;
  }
}

// nbr[row] = sum_j A3[row,j]*nw[j]
__global__ void k_nbr(const float* __restrict__ A3, const float* __restrict__ nw,
                      float* __restrict__ nbr){
  __shared__ float red[256];
  int row = blockIdx.x;
  float s = 0.f;
  for (int j = threadIdx.x; j < 1024; j += 256)
    s += A3[(size_t)row*1024 + j]*nw[j];
  red[threadIdx.x] = s; __syncthreads();
  for (int st = 128; st > 0; st >>= 1){
    if (threadIdx.x < st) red[threadIdx.x] += red[threadIdx.x+st];
    __syncthreads();
  }
  if (threadIdx.x == 0) nbr[row] = red[0];
}

// eff_w = A * gc_w (in place over A buffer, 3M elements)
__global__ void k_effw(float* __restrict__ A, const float* __restrict__ gcw){
  int idx = blockIdx.x*256 + threadIdx.x;
  A[idx] = A[idx]*gcw[idx];
}

// ---------------- main-loop GEMM (NT: out[i,j] = sum_p A(i,p)*W[j,p] + bias) ----------------
// A given as two segments (cols [0,K0) from A0/lda0, [K0,K) from A1/lda1).
// W given as four 1024-row segments selected by output column block.
// 32x64 tile, 256 threads, 2x4 per thread, TK=32.
__global__ __launch_bounds__(256) void k_gemm(
    const float* __restrict__ A0, int lda0, int K0,
    const float* __restrict__ A1, int lda1,
    const float* __restrict__ W0, const float* __restrict__ W1,
    const float* __restrict__ W2, const float* __restrict__ W3, int ldw,
    const float* __restrict__ b0, const float* __restrict__ b1,
    const float* __restrict__ b2, const float* __restrict__ b3,
    float* __restrict__ out, int ldc, int K)
{
  __shared__ float As[32][32];
  __shared__ float Ws[32][64];
  int j0 = blockIdx.x*64, i0 = blockIdx.y*32;
  int seg = j0 >> 10, jr = j0 & 1023;
  const float* W    = seg==0?W0: seg==1?W1: seg==2?W2:W3;
  const float* bias = seg==0?b0: seg==1?b1: seg==2?b2:b3;
  int tid = threadIdx.x, tx = tid & 15, ty = tid >> 4;
  float acc[2][4] = {};
  for (int k0 = 0; k0 < K; k0 += 32) {
    {
      int m = tid >> 3, kq = tid & 7;
      const float* Ap;
      if (k0 < K0) Ap = A0 + (size_t)(i0+m)*lda0 + k0;
      else         Ap = A1 + (size_t)(i0+m)*lda1 + (k0 - K0);
      float4 v = *(const float4*)(Ap + kq*4);
      As[kq*4+0][m]=v.x; As[kq*4+1][m]=v.y; As[kq*4+2][m]=v.z; As[kq*4+3][m]=v.w;
    }
    #pragma unroll
    for (int r = 0; r < 2; ++r) {
      int idx = tid + r*256;
      int n = idx >> 3, kq = idx & 7;
      float4 v = *(const float4*)(W + (size_t)(jr+n)*ldw + k0 + kq*4);
      Ws[kq*4+0][n]=v.x; Ws[kq*4+1][n]=v.y; Ws[kq*4+2][n]=v.z; Ws[kq*4+3][n]=v.w;
    }
    __syncthreads();
    #pragma unroll
    for (int k = 0; k < 32; ++k) {
      float2 a = *(const float2*)&As[k][ty*2];
      float4 w = *(const float4*)&Ws[k][tx*4];
      acc[0][0]+=a.x*w.x; acc[0][1]+=a.x*w.y; acc[0][2]+=a.x*w.z; acc[0][3]+=a.x*w.w;
      acc[1][0]+=a.y*w.x; acc[1][1]+=a.y*w.y; acc[1][2]+=a.y*w.z; acc[1][3]+=a.y*w.w;
    }
    __syncthreads();
  }
  float4 bv = make_float4(0.f,0.f,0.f,0.f);
  if (bias) bv = *(const float4*)(bias + jr + tx*4);
  #pragma unroll
  for (int r = 0; r < 2; ++r) {
    float4 o4 = make_float4(acc[r][0]+bv.x, acc[r][1]+bv.y, acc[r][2]+bv.z, acc[r][3]+bv.w);
    *(float4*)(out + (size_t)(i0+ty*2+r)*ldc + j0 + tx*4) = o4;
  }
}

// ---------------- gate update (both LSTMs fused) ----------------
__global__ void k_gates(const float* __restrict__ g, const float* __restrict__ rg,
                        const float* __restrict__ nbr,
                        float* __restrict__ H,  float* __restrict__ Cs,
                        float* __restrict__ rH, float* __restrict__ rCs){
  int idx = blockIdx.x*256 + threadIdx.x;      // BC*NN
  int i = idx >> 10, m = idx & 1023;
  const float* gi = g + (size_t)i*4096;
  float f  = sigf(gi[m]);
  float ig = sigf(gi[m+1024]);
  float o  = sigf(gi[m+2048]);
  float ct = tanhf(gi[m+3072]);
  float cs = f*(Cs[idx]*nbr[m]) + ig*ct;
  Cs[idx] = cs;
  H[idx]  = o*tanhf(cs);
  const float* ri = rg + (size_t)i*4096;
  float rf  = sigf(ri[m]);
  float rig = sigf(ri[m+1024]);
  float ro  = sigf(ri[m+2048]);
  float rct = tanhf(ri[m+3072]);
  float rcs = rf*rCs[idx] + rig*rct;
  rCs[idx] = rcs;
  rH[idx]  = ro*tanhf(rcs);
}

// ---------------- last-step statistics ----------------
// vars = [var1_0, var1_1, var2_0, var2_1]; one block per channel
__global__ void k_var(const float* __restrict__ Xlast, const float* __restrict__ gc,
                      float* __restrict__ vars){
  int ch = blockIdx.x;
  int tid = threadIdx.x;
  float s1=0.f,q1=0.f,s2=0.f,q2=0.f;
  for (int f = tid; f < 64*1024; f += 256) {
    int b = f >> 10, n = f & 1023;
    float v = Xlast[(size_t)(b*2+ch)*1024 + n];
    s1 += v; q1 += v*v;
  }
  for (int f = tid; f < 64*3072; f += 256) {
    int b = f / 3072, j = f % 3072;
    float v = gc[(size_t)(b*2+ch)*3072 + j];
    s2 += v; q2 += v*v;
  }
  __shared__ float red[256][4];
  red[tid][0]=s1; red[tid][1]=q1; red[tid][2]=s2; red[tid][3]=q2;
  __syncthreads();
  for (int st = 128; st > 0; st >>= 1){
    if (tid < st){
      red[tid][0]+=red[tid+st][0]; red[tid][1]+=red[tid+st][1];
      red[tid][2]+=red[tid+st][2]; red[tid][3]+=red[tid+st][3];
    }
    __syncthreads();
  }
  if (tid == 0){
    float n1 = 65536.f, n2 = 196608.f;
    vars[ch]   = (red[0][1] - red[0][0]*red[0][0]/n1) / (n1 - 1.f);
    vars[2+ch] = (red[0][3] - red[0][2]*red[0][2]/n2) / (n2 - 1.f);
  }
}

__global__ void k_pred(const float* __restrict__ H, const float* __restrict__ rH,
                       const float* __restrict__ vars, const float* __restrict__ cptr,
                       float* __restrict__ pred){
  int idx = blockIdx.x*256 + threadIdx.x;      // BC*NN
  int ch = (idx >> 10) & 1;
  float c0 = cptr[0];
  float v1 = vars[ch], v2 = vars[2+ch];
  pred[idx] = (H[idx]*v1*c0 + rH[idx]*v2) / (v1 + v2*c0);
}

// out[b*24576 + o*1024 + n] = sum_c pred[b,c,n]*cw[o*2+c] + cb[o]
__global__ void k_conv(const float* __restrict__ pred, const float* __restrict__ cw,
                       const float* __restrict__ cb, float* __restrict__ out){
  int idx = blockIdx.x*256 + threadIdx.x;      // 64*24*1024
  int n = idx & 1023;
  int on = idx >> 10;
  int o = on % 24, b = on / 24;
  float p0 = pred[(size_t)(b*2+0)*1024 + n];
  float p1 = pred[(size_t)(b*2+1)*1024 + n];
  out[idx] = p0*cw[o*2+0] + p1*cw[o*2+1] + cb[o];
}

// ---------------- launch ----------------
extern "C" void kernel_launch(void* const* d_in, const int* in_sizes, int n_in,
                              void* d_out, int out_size, void* d_ws, size_t ws_size,
                              hipStream_t stream) {
  const float* inputs = (const float*)d_in[0];
  const float* adj    = (const float*)d_in[1];
  const float* gcw    = (const float*)d_in[2];
  const float* Wf  = (const float*)d_in[3];  const float* bf_ = (const float*)d_in[4];
  const float* Wi  = (const float*)d_in[5];  const float* bi_ = (const float*)d_in[6];
  const float* Wo  = (const float*)d_in[7];  const float* bo_ = (const float*)d_in[8];
  const float* Wc  = (const float*)d_in[9];  const float* bc_ = (const float*)d_in[10];
  const float* rWf = (const float*)d_in[11]; const float* rbf = (const float*)d_in[12];
  const float* rWi = (const float*)d_in[13]; const float* rbi = (const float*)d_in[14];
  const float* rWo = (const float*)d_in[15]; const float* rbo = (const float*)d_in[16];
  const float* rWc = (const float*)d_in[17]; const float* rbc = (const float*)d_in[18];
  const float* nw     = (const float*)d_in[19];
  const float* cscal  = (const float*)d_in[20];
  const float* convw  = (const float*)d_in[21];
  const float* convb  = (const float*)d_in[22];
  float* out = (float*)d_out;

  float* ws = (float*)d_ws;
  size_t off = 0;
  float* X     = ws + off; off += (size_t)LS*BC*NN;   // 3145728
  float* tmpv  = ws + off; off += 1024;
  float* anorm = ws + off; off += (size_t)NN*NN;      // 1048576
  float* Abuf  = ws + off; off += (size_t)3*NN*NN;    // A1,A2,A3 -> eff_w in place
  float* nbrv  = ws + off; off += 1024;
  float* H     = ws + off; off += (size_t)BC*NN;
  float* Cs    = ws + off; off += (size_t)BC*NN;
  float* rH    = ws + off; off += (size_t)BC*NN;
  float* rCs   = ws + off; off += (size_t)BC*NN;
  float* gc    = ws + off; off += (size_t)BC*3*NN;    // 393216
  float* g     = ws + off; off += (size_t)BC*4*NN;    // 524288
  float* rg    = ws + off; off += (size_t)BC*4*NN;
  float* pred  = ws + off; off += (size_t)BC*NN;
  float* vars  = ws + off; off += 16;

  float* A1 = Abuf;
  float* A2 = Abuf + (size_t)NN*NN;
  float* A3 = Abuf + (size_t)2*NN*NN;
  float* eff = Abuf;  // after k_effw

  // preprocessing
  k_transpose<<<(LS*BC*NN)/256, 256, 0, stream>>>(inputs, X);
  k_colsum<<<NN/256, 256, 0, stream>>>(adj, tmpv);
  k_anorm<<<(NN*NN)/256, 256, 0, stream>>>(adj, tmpv, anorm, A1);
  dim3 gsq(16, 16);
  k_gemm_nn<<<gsq, 256, 0, stream>>>(A1, anorm, A2);
  k_gemm_nn<<<gsq, 256, 0, stream>>>(A2, anorm, A3);
  k_nbr<<<NN, 256, 0, stream>>>(A3, nw, nbrv);
  k_effw<<<(3*NN*NN)/256, 256, 0, stream>>>(Abuf, gcw);
  hipMemsetAsync(H, 0, (size_t)4*BC*NN*sizeof(float), stream);  // H,Cs,rH,rCs contiguous

  dim3 ggc(3*NN/64, BC/32);   // (48,4)
  dim3 gg(4*NN/64, BC/32);    // (64,4)
  for (int t = 0; t < LS; ++t) {
    const float* Xt = X + (size_t)t*BC*NN;
    // gc = Xt @ eff^T   (K=K0=1024, single A segment; W = eff rows, 3 segments)
    k_gemm<<<ggc, 256, 0, stream>>>(Xt, NN, NN, Xt, NN,
        eff, eff + (size_t)NN*NN, eff + (size_t)2*NN*NN, eff, NN,
        nullptr, nullptr, nullptr, nullptr,
        gc, 3*NN, NN);
    // rg = [Xt, rH] @ rWg^T + rbg
    k_gemm<<<gg, 256, 0, stream>>>(Xt, NN, NN, rH, NN,
        rWf, rWi, rWo, rWc, 2*NN,
        rbf, rbi, rbo, rbc,
        rg, 4*NN, 2*NN);
    // g = [gc, H] @ Wg^T + bg
    k_gemm<<<gg, 256, 0, stream>>>(gc, 3*NN, 3*NN, H, NN,
        Wf, Wi, Wo, Wc, 4*NN,
        bf_, bi_, bo_, bc_,
        g, 4*NN, 4*NN);
    k_gates<<<(BC*NN)/256, 256, 0, stream>>>(g, rg, nbrv, H, Cs, rH, rCs);
  }

  const float* Xlast = X + (size_t)(LS-1)*BC*NN;
  k_var<<<2, 256, 0, stream>>>(Xlast, gc, vars);
  k_pred<<<(BC*NN)/256, 256, 0, stream>>>(H, rH, vars, cscal, pred);
  k_conv<<<(64*24*1024)/256, 256, 0, stream>>>(pred, convw, convb, out);
}

// Round 2
// 1415.270 us; speedup vs baseline: 5.5669x; 5.5669x over previous
//
#include <hip/hip_runtime.h>
#include <cmath>

#define NN 1024
#define BC 128
#define LS 24

typedef unsigned short u16;
typedef __attribute__((ext_vector_type(4))) float f32x4;
typedef __attribute__((ext_vector_type(8))) short bf16x8;

typedef __attribute__((address_space(1))) const void* as1cv;
typedef __attribute__((address_space(3))) void* as3v;

#define GLD16(gp, lp) __builtin_amdgcn_global_load_lds((as1cv)(gp), (as3v)(lp), 16, 0, 0)

__device__ __forceinline__ float sigf(float x){ return 1.0f/(1.0f+expf(-x)); }

__device__ __forceinline__ u16 f2b(float x){
  union { float f; unsigned u; } v; v.f = x;
  unsigned r = v.u + 0x7FFFu + ((v.u >> 16) & 1u);
  return (u16)(r >> 16);
}
__device__ __forceinline__ float b2f(u16 b){
  union { unsigned u; float f; } v; v.u = ((unsigned)b) << 16;
  return v.f;
}

// ---------------- preprocessing ----------------

// Xb[t][i][n] (bf16) from inputs[i][n][t]; each thread owns one (i,n), loops t.
__global__ void k_transpose(const float* __restrict__ in, u16* __restrict__ Xb){
  int idx = blockIdx.x*256 + threadIdx.x;           // BC*NN
  const float* p = in + (size_t)idx*LS;
  #pragma unroll
  for (int t = 0; t < LS; ++t)
    Xb[(size_t)t*BC*NN + idx] = f2b(p[t]);
}

// column sums of adj, two-stage
__global__ void k_colsum1(const float* __restrict__ adj, float* __restrict__ part){
  int b = blockIdx.x;                // 64 blocks, 16 rows each
  for (int j = threadIdx.x; j < 1024; j += 256){
    float s = 0.f;
    for (int i = 0; i < 16; ++i) s += adj[(size_t)(b*16+i)*1024 + j];
    part[(size_t)b*1024 + j] = s;
  }
}
__global__ void k_colsum2(const float* __restrict__ part, float* __restrict__ tmp){
  int j = blockIdx.x*256 + threadIdx.x;
  float s = 0.f;
  for (int b = 0; b < 64; ++b) s += part[(size_t)b*1024 + j];
  tmp[j] = (s == 0.f) ? 1e-5f : s;
}

__global__ void k_anorm(const float* __restrict__ adj, const float* __restrict__ tmp,
                        float* __restrict__ anorm, float* __restrict__ A1){
  int idx = blockIdx.x*256 + threadIdx.x;           // 1M
  int i = idx >> 10;
  float v = tmp[i]*adj[idx];
  anorm[idx] = v;
  A1[idx] = fminf(v, 1.f);
}

// C = min(A@B, 1), 1024^3 fp32 (adjacency powers)
__global__ __launch_bounds__(256) void k_gemm_nn(const float* __restrict__ A,
                                                 const float* __restrict__ B,
                                                 float* __restrict__ C){
  __shared__ float As[16][64];
  __shared__ float Bs[16][64];
  int i0 = blockIdx.y*64, j0 = blockIdx.x*64;
  int tid = threadIdx.x;
  int tx = tid & 15, ty = tid >> 4;
  float acc[4][4] = {};
  for (int k0 = 0; k0 < 1024; k0 += 16) {
    {
      int m = tid >> 2, kq = tid & 3;
      float4 v = *(const float4*)(A + (size_t)(i0+m)*1024 + k0 + kq*4);
      As[kq*4+0][m]=v.x; As[kq*4+1][m]=v.y; As[kq*4+2][m]=v.z; As[kq*4+3][m]=v.w;
    }
    {
      int k = tid >> 6, j = tid & 63;
      #pragma unroll
      for (int r = 0; r < 4; ++r)
        Bs[k + r*4][j] = B[(size_t)(k0 + k + r*4)*1024 + j0 + j];
    }
    __syncthreads();
    #pragma unroll
    for (int k = 0; k < 16; ++k) {
      float4 a = *(const float4*)&As[k][ty*4];
      float4 b = *(const float4*)&Bs[k][tx*4];
      acc[0][0]+=a.x*b.x; acc[0][1]+=a.x*b.y; acc[0][2]+=a.x*b.z; acc[0][3]+=a.x*b.w;
      acc[1][0]+=a.y*b.x; acc[1][1]+=a.y*b.y; acc[1][2]+=a.y*b.z; acc[1][3]+=a.y*b.w;
      acc[2][0]+=a.z*b.x; acc[2][1]+=a.z*b.y; acc[2][2]+=a.z*b.z; acc[2][3]+=a.z*b.w;
      acc[3][0]+=a.w*b.x; acc[3][1]+=a.w*b.y; acc[3][2]+=a.w*b.z; acc[3][3]+=a.w*b.w;
    }
    __syncthreads();
  }
  #pragma unroll
  for (int r = 0; r < 4; ++r) {
    float4 o4 = make_float4(fminf(acc[r][0],1.f), fminf(acc[r][1],1.f),
                            fminf(acc[r][2],1.f), fminf(acc[r][3],1.f));
    *(float4*)(C + (size_t)(i0+ty*4+r)*1024 + j0 + tx*4) = o4;
  }
}

__global__ void k_nbr(const float* __restrict__ A3, const float* __restrict__ nw,
                      float* __restrict__ nbr){
  __shared__ float red[256];
  int row = blockIdx.x;
  float s = 0.f;
  for (int j = threadIdx.x; j < 1024; j += 256)
    s += A3[(size_t)row*1024 + j]*nw[j];
  red[threadIdx.x] = s; __syncthreads();
  for (int st = 128; st > 0; st >>= 1){
    if (threadIdx.x < st) red[threadIdx.x] += red[threadIdx.x+st];
    __syncthreads();
  }
  if (threadIdx.x == 0) nbr[row] = red[0];
}

// effb = bf16(A_powers * gc_w)
__global__ void k_effw(const float* __restrict__ A, const float* __restrict__ gcw,
                       u16* __restrict__ effb){
  int idx = blockIdx.x*256 + threadIdx.x;
  effb[idx] = f2b(A[idx]*gcw[idx]);
}

// pack gate weights: Wgxb[(seg*1024+j)][k<3072], WgHb[(seg*1024+j)][k-3072]
__global__ void k_packW(const float* __restrict__ Wf, const float* __restrict__ Wi,
                        const float* __restrict__ Wo, const float* __restrict__ Wc,
                        u16* __restrict__ Wgxb, u16* __restrict__ WgHb){
  int idx = blockIdx.x*256 + threadIdx.x;           // 4*1024*4096
  int k = idx & 4095; int r = idx >> 12;
  int seg = r >> 10, j = r & 1023;
  const float* W = seg==0?Wf: seg==1?Wi: seg==2?Wo:Wc;
  float v = W[(size_t)j*4096 + k];
  if (k < 3072) Wgxb[(size_t)r*3072 + k] = f2b(v);
  else          WgHb[(size_t)r*1024 + (k-3072)] = f2b(v);
}
__global__ void k_packrW(const float* __restrict__ rWf, const float* __restrict__ rWi,
                         const float* __restrict__ rWo, const float* __restrict__ rWc,
                         u16* __restrict__ rWgxb, u16* __restrict__ rWgHb){
  int idx = blockIdx.x*256 + threadIdx.x;           // 4*1024*2048
  int k = idx & 2047; int r = idx >> 11;
  int seg = r >> 10, j = r & 1023;
  const float* W = seg==0?rWf: seg==1?rWi: seg==2?rWo:rWc;
  float v = W[(size_t)j*2048 + k];
  if (k < 1024) rWgxb[(size_t)r*1024 + k] = f2b(v);
  else          rWgHb[(size_t)r*1024 + (k-1024)] = f2b(v);
}
__global__ void k_packbias(const float* __restrict__ bf_, const float* __restrict__ bi_,
                           const float* __restrict__ bo_, const float* __restrict__ bc_,
                           const float* __restrict__ rbf, const float* __restrict__ rbi,
                           const float* __restrict__ rbo, const float* __restrict__ rbc,
                           float* __restrict__ bg, float* __restrict__ rbg){
  int idx = blockIdx.x*256 + threadIdx.x;           // 4096
  int seg = idx >> 10, j = idx & 1023;
  bg[idx]  = (seg==0?bf_: seg==1?bi_: seg==2?bo_:bc_)[j];
  rbg[idx] = (seg==0?rbf: seg==1?rbi: seg==2?rbo:rbc)[j];
}

// ---------------- bf16 MFMA NT GEMM core ----------------
// out[i,j] = sum_k A[i,k]*B[j,k] (+bias[j]) (+add[i,j]); A,B row-major stride K.
// 128x128 tile, 4 waves (2x2 of 64x64), BK=64, global_load_lds w/ XOR-swizzled source.
__device__ __forceinline__ void mfma_tile(
    const u16* __restrict__ A, const u16* __restrict__ Bw, int K,
    const float* __restrict__ bias, const float* __restrict__ add, int ldadd,
    float* __restrict__ outf, u16* __restrict__ outb, int ldc)
{
  __shared__ u16 ldsA[128*64];
  __shared__ u16 ldsB[128*64];
  const int tid  = threadIdx.x;
  const int lane = tid & 63;
  const int w    = tid >> 6;
  const int wr   = (w >> 1) * 64;
  const int wc   = (w & 1) * 64;
  f32x4 acc[4][4] = {};

  const int lrow = lane >> 3;                 // 0..7 within 8-row chunk
  const int srck = ((lane & 7) ^ lrow) * 8;   // pre-swizzled k-group (elements)

  for (int k0 = 0; k0 < K; k0 += 64) {
    #pragma unroll
    for (int c = 0; c < 4; ++c) {
      int row = w*32 + c*8;                   // wave-uniform chunk base
      GLD16(A  + (size_t)(row + lrow)*K + k0 + srck, &ldsA[row*64]);
      GLD16(Bw + (size_t)(row + lrow)*K + k0 + srck, &ldsB[row*64]);
    }
    __syncthreads();   // drains vmcnt before barrier (compiler-inserted)
    #pragma unroll
    for (int kk = 0; kk < 2; ++kk) {
      bf16x8 af[4], bfr[4];
      #pragma unroll
      for (int mi = 0; mi < 4; ++mi) {
        int row = wr + mi*16 + (lane & 15);
        int grp = (kk*4 + (lane >> 4)) ^ (row & 7);
        af[mi] = *(const bf16x8*)&ldsA[row*64 + grp*8];
      }
      #pragma unroll
      for (int ni = 0; ni < 4; ++ni) {
        int row = wc + ni*16 + (lane & 15);
        int grp = (kk*4 + (lane >> 4)) ^ (row & 7);
        bfr[ni] = *(const bf16x8*)&ldsB[row*64 + grp*8];
      }
      #pragma unroll
      for (int mi = 0; mi < 4; ++mi)
        #pragma unroll
        for (int ni = 0; ni < 4; ++ni)
          acc[mi][ni] = __builtin_amdgcn_mfma_f32_16x16x32_bf16(af[mi], bfr[ni], acc[mi][ni], 0, 0, 0);
    }
    __syncthreads();
  }
  #pragma unroll
  for (int mi = 0; mi < 4; ++mi) {
    #pragma unroll
    for (int ni = 0; ni < 4; ++ni) {
      int col = wc + ni*16 + (lane & 15);
      #pragma unroll
      for (int q = 0; q < 4; ++q) {
        int row = wr + mi*16 + (lane >> 4)*4 + q;
        float v = acc[mi][ni][q];
        if (bias) v += bias[col];
        if (add)  v += add[(size_t)row*ldadd + col];
        if (outf) outf[(size_t)row*ldc + col] = v;
        if (outb) outb[(size_t)row*ldc + col] = f2b(v);
      }
    }
  }
}

__global__ __launch_bounds__(256) void k_mfma_nt(
    const u16* __restrict__ A, const u16* __restrict__ B, int K,
    const float* __restrict__ bias, float* __restrict__ outf,
    u16* __restrict__ outb, int ldc)
{
  size_t i0 = (size_t)blockIdx.y * 128, j0 = (size_t)blockIdx.x * 128;
  mfma_tile(A + i0*K, B + j0*K, K,
            bias ? bias + j0 : nullptr, nullptr, 0,
            outf ? outf + i0*ldc + j0 : nullptr,
            outb ? outb + i0*ldc + j0 : nullptr, ldc);
}

// per-step: g = gpre_t + Hb@WgHb^T ; rg = rpre_t + rHb@rWgHb^T   (job = blockIdx.y)
__global__ __launch_bounds__(256) void k_step_gemm(
    const u16* __restrict__ Hb, const u16* __restrict__ rHb,
    const u16* __restrict__ WgHb, const u16* __restrict__ rWgHb,
    const float* __restrict__ gpre_t, const float* __restrict__ rpre_t,
    float* __restrict__ g, float* __restrict__ rg)
{
  size_t j0 = (size_t)blockIdx.x * 128;
  int job = blockIdx.y;
  const u16* A = job ? rHb : Hb;
  const u16* B = (job ? rWgHb : WgHb) + j0*1024;
  const float* add = (job ? rpre_t : gpre_t) + j0;
  float* o = (job ? rg : g) + j0;
  mfma_tile(A, B, 1024, nullptr, add, 4096, o, nullptr, 4096);
}

// ---------------- gate update ----------------
__global__ void k_gates(const float* __restrict__ g, const float* __restrict__ rg,
                        const float* __restrict__ nbr,
                        float* __restrict__ H,  float* __restrict__ Cs,
                        float* __restrict__ rH, float* __restrict__ rCs,
                        u16* __restrict__ Hb, u16* __restrict__ rHb){
  int idx = blockIdx.x*256 + threadIdx.x;      // BC*NN
  int i = idx >> 10, m = idx & 1023;
  const float* gi = g + (size_t)i*4096;
  float f  = sigf(gi[m]);
  float ig = sigf(gi[m+1024]);
  float o  = sigf(gi[m+2048]);
  float ct = tanhf(gi[m+3072]);
  float cs = f*(Cs[idx]*nbr[m]) + ig*ct;
  Cs[idx] = cs;
  float h = o*tanhf(cs);
  H[idx] = h; Hb[idx] = f2b(h);
  const float* ri = rg + (size_t)i*4096;
  float rf  = sigf(ri[m]);
  float rig = sigf(ri[m+1024]);
  float ro  = sigf(ri[m+2048]);
  float rct = tanhf(ri[m+3072]);
  float rcs = rf*rCs[idx] + rig*rct;
  rCs[idx] = rcs;
  float rh = ro*tanhf(rcs);
  rH[idx] = rh; rHb[idx] = f2b(rh);
}

// ---------------- last-step statistics (two-stage) ----------------
__global__ void k_var1(const u16* __restrict__ Xl, const u16* __restrict__ gcl,
                       float* __restrict__ part){
  int ch = blockIdx.x & 1, seg = blockIdx.x >> 1;   // 64 blocks
  int tid = threadIdx.x;
  float s1=0.f,q1=0.f,s2=0.f,q2=0.f;
  for (int bb = 0; bb < 2; ++bb){
    int row = (seg*2+bb)*2 + ch;
    const u16* xr = Xl + (size_t)row*1024;
    for (int n = tid; n < 1024; n += 256){ float v = b2f(xr[n]); s1 += v; q1 += v*v; }
    const u16* gr = gcl + (size_t)row*3072;
    for (int n = tid; n < 3072; n += 256){ float v = b2f(gr[n]); s2 += v; q2 += v*v; }
  }
  __shared__ float red[256][4];
  red[tid][0]=s1; red[tid][1]=q1; red[tid][2]=s2; red[tid][3]=q2;
  __syncthreads();
  for (int st = 128; st > 0; st >>= 1){
    if (tid < st){ for (int z = 0; z < 4; ++z) red[tid][z] += red[tid+st][z]; }
    __syncthreads();
  }
  if (tid == 0){ for (int z = 0; z < 4; ++z) part[(size_t)blockIdx.x*4 + z] = red[0][z]; }
}
__global__ void k_var2(const float* __restrict__ part, float* __restrict__ vars){
  int tid = threadIdx.x;
  if (tid < 2){
    float s1=0.f,q1=0.f,s2=0.f,q2=0.f;
    for (int seg = 0; seg < 32; ++seg){
      const float* p = part + (size_t)(seg*2+tid)*4;
      s1 += p[0]; q1 += p[1]; s2 += p[2]; q2 += p[3];
    }
    float n1 = 65536.f, n2 = 196608.f;
    vars[tid]   = (q1 - s1*s1/n1) / (n1 - 1.f);
    vars[2+tid] = (q2 - s2*s2/n2) / (n2 - 1.f);
  }
}

__global__ void k_pred(const float* __restrict__ H, const float* __restrict__ rH,
                       const float* __restrict__ vars, const float* __restrict__ cptr,
                       float* __restrict__ pred){
  int idx = blockIdx.x*256 + threadIdx.x;
  int ch = (idx >> 10) & 1;
  float c0 = cptr[0];
  float v1 = vars[ch], v2 = vars[2+ch];
  pred[idx] = (H[idx]*v1*c0 + rH[idx]*v2) / (v1 + v2*c0);
}

__global__ void k_conv(const float* __restrict__ pred, const float* __restrict__ cw,
                       const float* __restrict__ cb, float* __restrict__ out){
  int idx = blockIdx.x*256 + threadIdx.x;      // 64*24*1024
  int n = idx & 1023;
  int on = idx >> 10;
  int o = on % 24, b = on / 24;
  float p0 = pred[(size_t)(b*2+0)*1024 + n];
  float p1 = pred[(size_t)(b*2+1)*1024 + n];
  out[idx] = p0*cw[o*2+0] + p1*cw[o*2+1] + cb[o];
}

// ---------------- launch ----------------
extern "C" void kernel_launch(void* const* d_in, const int* in_sizes, int n_in,
                              void* d_out, int out_size, void* d_ws, size_t ws_size,
                              hipStream_t stream) {
  const float* inputs = (const float*)d_in[0];
  const float* adj    = (const float*)d_in[1];
  const float* gcw    = (const float*)d_in[2];
  const float* Wf  = (const float*)d_in[3];  const float* bf_ = (const float*)d_in[4];
  const float* Wi  = (const float*)d_in[5];  const float* bi_ = (const float*)d_in[6];
  const float* Wo  = (const float*)d_in[7];  const float* bo_ = (const float*)d_in[8];
  const float* Wc  = (const float*)d_in[9];  const float* bc_ = (const float*)d_in[10];
  const float* rWf = (const float*)d_in[11]; const float* rbf = (const float*)d_in[12];
  const float* rWi = (const float*)d_in[13]; const float* rbi = (const float*)d_in[14];
  const float* rWo = (const float*)d_in[15]; const float* rbo = (const float*)d_in[16];
  const float* rWc = (const float*)d_in[17]; const float* rbc = (const float*)d_in[18];
  const float* nw     = (const float*)d_in[19];
  const float* cscal  = (const float*)d_in[20];
  const float* convw  = (const float*)d_in[21];
  const float* convb  = (const float*)d_in[22];
  float* out = (float*)d_out;

  char* cur = (char*)d_ws;
  auto alloc = [&](size_t bytes) -> void* {
    void* p = cur; cur += (bytes + 255) & ~(size_t)255; return p;
  };
  u16*   Xb    = (u16*)  alloc((size_t)LS*BC*NN*2);       // 24x128x1024 bf16
  float* csum  = (float*)alloc((size_t)64*1024*4);
  float* tmpv  = (float*)alloc(1024*4);
  float* anorm = (float*)alloc((size_t)NN*NN*4);
  float* Abuf  = (float*)alloc((size_t)3*NN*NN*4);        // A1,A2,A3
  float* nbrv  = (float*)alloc(1024*4);
  u16*   effb  = (u16*)  alloc((size_t)3*NN*NN*2);
  u16*   Wgxb  = (u16*)  alloc((size_t)4096*3072*2);
  u16*   WgHb  = (u16*)  alloc((size_t)4096*1024*2);
  u16*   rWgxb = (u16*)  alloc((size_t)4096*1024*2);
  u16*   rWgHb = (u16*)  alloc((size_t)4096*1024*2);
  float* bgp   = (float*)alloc(4096*4);
  float* rbgp  = (float*)alloc(4096*4);
  u16*   gcb   = (u16*)  alloc((size_t)3072*3072*2);
  float* gpre  = (float*)alloc((size_t)3072*4096*4);
  float* rpre  = (float*)alloc((size_t)3072*4096*4);
  float* g     = (float*)alloc((size_t)BC*4096*4);
  float* rg    = (float*)alloc((size_t)BC*4096*4);
  float* H     = (float*)alloc((size_t)BC*NN*4);
  float* Cs    = (float*)alloc((size_t)BC*NN*4);
  float* rH    = (float*)alloc((size_t)BC*NN*4);
  float* rCs   = (float*)alloc((size_t)BC*NN*4);
  u16*   Hb    = (u16*)  alloc((size_t)BC*NN*2);
  u16*   rHb   = (u16*)  alloc((size_t)BC*NN*2);
  float* pred  = (float*)alloc((size_t)BC*NN*4);
  float* vars  = (float*)alloc(16*4);
  float* part  = (float*)alloc(64*4*4);

  float* A1 = Abuf;
  float* A2 = Abuf + (size_t)NN*NN;
  float* A3 = Abuf + (size_t)2*NN*NN;

  // preprocessing
  k_transpose<<<(BC*NN)/256, 256, 0, stream>>>(inputs, Xb);
  k_colsum1<<<64, 256, 0, stream>>>(adj, csum);
  k_colsum2<<<4, 256, 0, stream>>>(csum, tmpv);
  k_anorm<<<(NN*NN)/256, 256, 0, stream>>>(adj, tmpv, anorm, A1);
  dim3 gsq(16, 16);
  k_gemm_nn<<<gsq, 256, 0, stream>>>(A1, anorm, A2);
  k_gemm_nn<<<gsq, 256, 0, stream>>>(A2, anorm, A3);
  k_nbr<<<NN, 256, 0, stream>>>(A3, nw, nbrv);
  k_effw<<<(3*NN*NN)/256, 256, 0, stream>>>(Abuf, gcw, effb);
  k_packW<<<(4*1024*4096)/256, 256, 0, stream>>>(Wf, Wi, Wo, Wc, Wgxb, WgHb);
  k_packrW<<<(4*1024*2048)/256, 256, 0, stream>>>(rWf, rWi, rWo, rWc, rWgxb, rWgHb);
  k_packbias<<<16, 256, 0, stream>>>(bf_, bi_, bo_, bc_, rbf, rbi, rbo, rbc, bgp, rbgp);

  // big GEMMs (bf16 MFMA)
  dim3 ggc(24, 24);   // gc_all: 3072x3072, K=1024 -> bf16 out
  k_mfma_nt<<<ggc, 256, 0, stream>>>(Xb, effb, 1024, nullptr, nullptr, gcb, 3072);
  dim3 gpr(32, 24);   // rpre: 3072x4096, K=1024
  k_mfma_nt<<<gpr, 256, 0, stream>>>(Xb, rWgxb, 1024, rbgp, rpre, nullptr, 4096);
  // gpre: 3072x4096, K=3072
  k_mfma_nt<<<gpr, 256, 0, stream>>>(gcb, Wgxb, 3072, bgp, gpre, nullptr, 4096);

  // zero state (H,Cs,rH,rCs fp32 + Hb,rHb bf16 contiguous)
  hipMemsetAsync(H, 0, (size_t)4*BC*NN*4 + (size_t)2*BC*NN*2, stream);

  dim3 gstep(32, 2);
  for (int t = 0; t < LS; ++t) {
    k_step_gemm<<<gstep, 256, 0, stream>>>(Hb, rHb, WgHb, rWgHb,
        gpre + (size_t)t*BC*4096, rpre + (size_t)t*BC*4096, g, rg);
    k_gates<<<(BC*NN)/256, 256, 0, stream>>>(g, rg, nbrv, H, Cs, rH, rCs, Hb, rHb);
  }

  k_var1<<<64, 256, 0, stream>>>(Xb + (size_t)(LS-1)*BC*NN, gcb + (size_t)(LS-1)*BC*3072, part);
  k_var2<<<1, 64, 0, stream>>>(part, vars);
  k_pred<<<(BC*NN)/256, 256, 0, stream>>>(H, rH, vars, cscal, pred);
  k_conv<<<(64*24*1024)/256, 256, 0, stream>>>(pred, convw, convb, out);
}